// Round 3
// baseline (754.192 us; speedup 1.0000x reference)
//
#include <hip/hip_runtime.h>
#include <hip/hip_bf16.h>

// SparseToDense: scatter features [N,32] into dense [B=4, C=32, D=64, H=64, W=64]
// flat_idx is a linear index into B*D*H*W (NDHWC site order); output is NCDHW.
// DHW = 64*64*64 = 262144 = 2^18.
//
// Duplicate indices exist (randint over 1.05M sites, 400k draws -> ~70k dups)
//   -> must atomicAdd, not store.
// Harness converts integer inputs to int32 ("integer -> const int*") even though
//   the reference says int64 -- reading as long long caused OOB faults (R1/R2).
// Zero-fill via kernel, not hipMemsetAsync (graph-capture safety).

#define DHW_LOG2 18
#define DHW (1 << DHW_LOG2)
#define C_CH 32

__global__ __launch_bounds__(256) void zero_kernel(float4* __restrict__ out, int n4)
{
    int t = blockIdx.x * blockDim.x + threadIdx.x;
    if (t < n4) out[t] = make_float4(0.f, 0.f, 0.f, 0.f);
}

__global__ __launch_bounds__(256) void scatter_kernel(
    const float* __restrict__ feats,
    const int* __restrict__ flat_idx,
    float* __restrict__ out,
    int n_active)
{
    int t = blockIdx.x * blockDim.x + threadIdx.x;
    int i = t >> 5;        // point index
    int c = t & 31;        // channel
    if (i >= n_active) return;

    int s = flat_idx[i];                    // 32 adjacent lanes read same value -> L1 broadcast
    int b  = s >> DHW_LOG2;                 // batch
    int sp = s & (DHW - 1);                 // spatial within batch

    float v = feats[(size_t)i * C_CH + c];  // coalesced: lane c reads feats[i*32+c]

    // out[b][c][d][h][w] = out[(b*32 + c) * DHW + sp]
    atomicAdd(&out[(((size_t)b * C_CH + c) << DHW_LOG2) + sp], v);
}

extern "C" void kernel_launch(void* const* d_in, const int* in_sizes, int n_in,
                              void* d_out, int out_size, void* d_ws, size_t ws_size,
                              hipStream_t stream) {
    const float* feats = (const float*)d_in[0];
    const int*   idx   = (const int*)d_in[1];
    float*       out   = (float*)d_out;

    int n_active = in_sizes[1];   // 400000 (flat_idx element count)

    // Zero d_out (poisoned 0xAA before every timed call). out_size = 4*32*2^18,
    // divisible by 4 -> float4 fill.
    int n4 = out_size >> 2;
    int zblock = 256;
    int zgrid = (n4 + zblock - 1) / zblock;
    zero_kernel<<<zgrid, zblock, 0, stream>>>((float4*)out, n4);

    int total  = n_active * C_CH;           // 12.8M threads
    int block  = 256;
    int grid   = (total + block - 1) / block;
    scatter_kernel<<<grid, block, 0, stream>>>(feats, idx, out, n_active);
}

// Round 4
// 204.910 us; speedup vs baseline: 3.6806x; 3.6806x over previous
//
#include <hip/hip_runtime.h>
#include <hip/hip_bf16.h>

// SparseToDense: scatter features [N,32] into dense [B=4, C=32, D=64, H=64, W=64].
// flat_idx (int32 on device -- harness converts integers to int) indexes B*D*H*W
// sites in (b,d,h,w) order; output is NCDHW. DHW = 2^18.
//
// R3 post-mortem: 12.8M scattered 4B float atomics cost 607us and 400 MB of
// TCC write traffic (32 B write-through per atomic). Fix: invert the scatter.
//   1) head[site] chains built with 400k int atomicExch (4 MB array, L2-resident)
//   2) gather kernel: one thread per site walks its chain, accumulates 32
//      channels in registers, writes output fully coalesced exactly once.
// No float atomics, no zero-fill of the 134 MB output.

#define DHW_LOG2 18
#define DHW (1 << DHW_LOG2)
#define C_CH 32
#define N_SITES_TOTAL (4 * DHW)   // B=4

__global__ __launch_bounds__(256) void init_head_kernel(int* __restrict__ head, int n)
{
    int t = blockIdx.x * blockDim.x + threadIdx.x;
    if (t < n) head[t] = -1;
}

__global__ __launch_bounds__(256) void build_chains_kernel(
    const int* __restrict__ flat_idx,
    int* __restrict__ head,
    int* __restrict__ next,
    int n_active)
{
    int i = blockIdx.x * blockDim.x + threadIdx.x;
    if (i >= n_active) return;
    int s = flat_idx[i];
    int prev = atomicExch(&head[s], i);   // device-scope int atomic, 4 MB array
    next[i] = prev;
}

__global__ __launch_bounds__(256) void gather_kernel(
    const float* __restrict__ feats,
    const int* __restrict__ head,
    const int* __restrict__ next,
    float* __restrict__ out)
{
    int S = blockIdx.x * blockDim.x + threadIdx.x;   // global site, lane-consecutive
    if (S >= N_SITES_TOTAL) return;

    int b  = S >> DHW_LOG2;
    int sp = S & (DHW - 1);

    float4 a0 = make_float4(0.f, 0.f, 0.f, 0.f);
    float4 a1 = a0, a2 = a0, a3 = a0, a4 = a0, a5 = a0, a6 = a0, a7 = a0;

    int p = head[S];                      // coalesced 4B reads across lanes
    while (p != -1) {
        const float4* row = (const float4*)(feats + (size_t)p * C_CH);  // 128B-aligned
        float4 f0 = row[0], f1 = row[1], f2 = row[2], f3 = row[3];
        float4 f4 = row[4], f5 = row[5], f6 = row[6], f7 = row[7];
        a0.x += f0.x; a0.y += f0.y; a0.z += f0.z; a0.w += f0.w;
        a1.x += f1.x; a1.y += f1.y; a1.z += f1.z; a1.w += f1.w;
        a2.x += f2.x; a2.y += f2.y; a2.z += f2.z; a2.w += f2.w;
        a3.x += f3.x; a3.y += f3.y; a3.z += f3.z; a3.w += f3.w;
        a4.x += f4.x; a4.y += f4.y; a4.z += f4.z; a4.w += f4.w;
        a5.x += f5.x; a5.y += f5.y; a5.z += f5.z; a5.w += f5.w;
        a6.x += f6.x; a6.y += f6.y; a6.z += f6.z; a6.w += f6.w;
        a7.x += f7.x; a7.y += f7.y; a7.z += f7.z; a7.w += f7.w;
        p = next[p];
    }

    // out[(b*32 + c) << 18 | sp]; lane-consecutive sp -> coalesced per channel.
    float* o = out + (((size_t)b * C_CH) << DHW_LOG2) + sp;
    float acc[C_CH] = {
        a0.x, a0.y, a0.z, a0.w,  a1.x, a1.y, a1.z, a1.w,
        a2.x, a2.y, a2.z, a2.w,  a3.x, a3.y, a3.z, a3.w,
        a4.x, a4.y, a4.z, a4.w,  a5.x, a5.y, a5.z, a5.w,
        a6.x, a6.y, a6.z, a6.w,  a7.x, a7.y, a7.z, a7.w };
    #pragma unroll
    for (int c = 0; c < C_CH; ++c)
        o[(size_t)c << DHW_LOG2] = acc[c];
}

// ---- fallback (R3 behavior) if workspace is too small ----
__global__ __launch_bounds__(256) void zero_kernel(float4* __restrict__ out, int n4)
{
    int t = blockIdx.x * blockDim.x + threadIdx.x;
    if (t < n4) out[t] = make_float4(0.f, 0.f, 0.f, 0.f);
}

__global__ __launch_bounds__(256) void scatter_atomic_kernel(
    const float* __restrict__ feats,
    const int* __restrict__ flat_idx,
    float* __restrict__ out,
    int n_active)
{
    int t = blockIdx.x * blockDim.x + threadIdx.x;
    int i = t >> 5, c = t & 31;
    if (i >= n_active) return;
    int s = flat_idx[i];
    atomicAdd(&out[(((size_t)(s >> DHW_LOG2) * C_CH + c) << DHW_LOG2) + (s & (DHW - 1))],
              feats[(size_t)i * C_CH + c]);
}

extern "C" void kernel_launch(void* const* d_in, const int* in_sizes, int n_in,
                              void* d_out, int out_size, void* d_ws, size_t ws_size,
                              hipStream_t stream) {
    const float* feats = (const float*)d_in[0];
    const int*   idx   = (const int*)d_in[1];
    float*       out   = (float*)d_out;
    int n_active = in_sizes[1];   // 400000

    size_t head_bytes = (size_t)N_SITES_TOTAL * sizeof(int);      // 4 MB
    size_t next_bytes = (size_t)n_active * sizeof(int);           // 1.6 MB

    if (ws_size >= head_bytes + next_bytes) {
        int* head = (int*)d_ws;
        int* next = (int*)((char*)d_ws + head_bytes);

        init_head_kernel<<<(N_SITES_TOTAL + 255) / 256, 256, 0, stream>>>(head, N_SITES_TOTAL);
        build_chains_kernel<<<(n_active + 255) / 256, 256, 0, stream>>>(idx, head, next, n_active);
        gather_kernel<<<(N_SITES_TOTAL + 255) / 256, 256, 0, stream>>>(feats, head, next, out);
    } else {
        // fallback: R3 atomic path
        int n4 = out_size >> 2;
        zero_kernel<<<(n4 + 255) / 256, 256, 0, stream>>>((float4*)out, n4);
        int total = n_active * C_CH;
        scatter_atomic_kernel<<<(total + 255) / 256, 256, 0, stream>>>(feats, idx, out, n_active);
    }
}